// Round 11
// baseline (191.516 us; speedup 1.0000x reference)
//
#include <hip/hip_runtime.h>
#include <hip/hip_bf16.h>
#include <math.h>

#define B_SZ    8
#define T_LEN   4096
#define DIN     256
#define DOUT    256
#define NST     512
#define M_ROWS  (B_SZ * T_LEN)   // 32768
#define N1      (2 * NST)        // 1024: cols [0,512)=real plane, [512,1024)=imag plane
#define K2      (N1 + DIN)       // 1280
#define CHL     128              // scan chunk length
#define NCH     (T_LEN / CHL)    // 32

typedef __attribute__((ext_vector_type(8))) short bf16x8;
typedef __attribute__((ext_vector_type(4))) float f32x4;
typedef __hip_bfloat16 bf16;

// ws byte offsets (baseline layout)
#define OFF_UBF  67108864
#define OFF_WP   83886080
#define OFF_W2   84410368
#define OFF_LAM  85065728
#define OFF_LAML 85069824
#define OFF_SSUM 85073920

__device__ __forceinline__ void gl_lds16(const bf16* g, bf16* l) {
    __builtin_amdgcn_global_load_lds(
        (const __attribute__((address_space(1))) void*)g,
        (__attribute__((address_space(3))) void*)l, 16, 0, 0);
}

// ---- prep (baseline verbatim) ----
__global__ __launch_bounds__(256) void prep(const float* __restrict__ u,
        const float* __restrict__ nu_log, const float* __restrict__ theta_log,
        const float* __restrict__ gamma_log,
        const float* __restrict__ B_real, const float* __restrict__ B_imag,
        const float* __restrict__ C_real, const float* __restrict__ C_imag,
        const float* __restrict__ Dm,
        bf16* __restrict__ ub, bf16* __restrict__ Wp, bf16* __restrict__ W2,
        float* __restrict__ lam, float* __restrict__ lamL) {
    int bid = blockIdx.x, tid = threadIdx.x;
    if (bid < 8192) {                       // u -> bf16
        int i = bid * 256 + tid;
        float4 v = ((const float4*)u)[i];
        union { bf16 h[4]; uint2 u2; } p;
        p.h[0] = __float2bfloat16(v.x); p.h[1] = __float2bfloat16(v.y);
        p.h[2] = __float2bfloat16(v.z); p.h[3] = __float2bfloat16(v.w);
        ((uint2*)ub)[i] = p.u2;
    } else if (bid < 9216) {                // Wp (split planes) + lam/lamL
        int c = bid - 8192;                 // 0..1023
        int n = c & (NST - 1);
        float g = expf(gamma_log[n]);
        const float* src = (c < NST) ? (B_real + (size_t)n * DIN)
                                     : (B_imag + (size_t)n * DIN);
        Wp[(size_t)c * DIN + tid] = __float2bfloat16(g * src[tid]);
        int idx = c * 256 + tid;
        if (idx < NST) {
            float lm = expf(-expf(nu_log[idx]));
            float th = expf(theta_log[idx]);
            float lr = lm * cosf(th), li = lm * sinf(th);
            lam[idx] = lr; lam[NST + idx] = li;
            float ar = lr, ai = li;
#pragma unroll
            for (int q = 0; q < 7; ++q) {   // lambda^128
                float nr = ar * ar - ai * ai;
                float ni = 2.f * ar * ai;
                ar = nr; ai = ni;
            }
            lamL[idx] = ar; lamL[NST + idx] = ai;
        }
    } else {                                // W2 = [2Cr | -2Ci | D] split
        int idx = (bid - 9216) * 256 + tid;
        if (idx < DOUT * K2) {
            int o = idx / K2, c = idx - o * K2;
            float v;
            if (c < NST)            v =  2.0f * C_real[(size_t)o * NST + c];
            else if (c < 2 * NST)   v = -2.0f * C_imag[(size_t)o * NST + (c - NST)];
            else                    v =  Dm[(size_t)o * DIN + (c - 2 * NST)];
            W2[idx] = __float2bfloat16(v);
        }
    }
}

// ---- GEMM1 v7: BK=64 (4 K-steps, 32 MFMA/wave per barrier), dbuf
// __syncthreads structure (verified), T2 both-sides XOR swizzle on the
// [128][64] LDS tiles (rule #21: linear gl_lds dest + inverse-swizzled
// GLOBAL source chunk + swizzled read chunk). Mirror of R10's verified
// gemm2 transform. Fragments carry identical values in identical k-order
// -> Bu bitwise identical. LDS 64 KB (union with Cs) -> 2 blocks/CU. ----
__global__ __launch_bounds__(256) void gemm1(const bf16* __restrict__ u,
                                             const bf16* __restrict__ Wp,
                                             bf16* __restrict__ Bu) {
    __shared__ union {
        bf16 ab[2][2][128 * 64];   // [buf][A=0/B=1] 64 KB
        bf16 cs[128 * 136];        // epilogue C-tile (+8 pad), 34.8 KB
    } sm;
    const int tid = threadIdx.x;
    const int m0 = blockIdx.x * 128, n0 = blockIdx.y * 128;
    const int lane = tid & 63, w = tid >> 6;
    const int wm = (w >> 1) * 64, wn = (w & 1) * 64;
    const int lr16 = lane & 15;
    const int srow = tid >> 3;                        // 0..31: row within 32-row quarter
    const int scolx = ((tid & 7) ^ (srow & 7)) * 8;   // inverse-swizzled global col chunk
    // quarters start at rows 0/32/64/96 (multiples of 8 -> same (row&7) = srow&7)

#define G1STAGE(buf, k0) do {                                                                        \
        gl_lds16(u  + (size_t)(m0 + srow) * DIN + (k0) + scolx,       &sm.ab[buf][0][tid * 8]);        \
        gl_lds16(u  + (size_t)(m0 + 32 + srow) * DIN + (k0) + scolx,  &sm.ab[buf][0][2048 + tid * 8]); \
        gl_lds16(u  + (size_t)(m0 + 64 + srow) * DIN + (k0) + scolx,  &sm.ab[buf][0][4096 + tid * 8]); \
        gl_lds16(u  + (size_t)(m0 + 96 + srow) * DIN + (k0) + scolx,  &sm.ab[buf][0][6144 + tid * 8]); \
        gl_lds16(Wp + (size_t)(n0 + srow) * DIN + (k0) + scolx,       &sm.ab[buf][1][tid * 8]);        \
        gl_lds16(Wp + (size_t)(n0 + 32 + srow) * DIN + (k0) + scolx,  &sm.ab[buf][1][2048 + tid * 8]); \
        gl_lds16(Wp + (size_t)(n0 + 64 + srow) * DIN + (k0) + scolx,  &sm.ab[buf][1][4096 + tid * 8]); \
        gl_lds16(Wp + (size_t)(n0 + 96 + srow) * DIN + (k0) + scolx,  &sm.ab[buf][1][6144 + tid * 8]); \
    } while (0)

    f32x4 acc[4][4] = {};
    G1STAGE(0, 0);                     // panel 0
    __syncthreads();
    for (int t = 0; t < 4; ++t) {
        const int cur = t & 1;
        if (t < 3) G1STAGE(cur ^ 1, (t + 1) * 64);   // prefetch next panel
#pragma unroll
        for (int ks = 0; ks < 2; ++ks) {             // two 32-wide sub-panels, ascending k
            const int gck = ks * 4 + (lane >> 4);    // global 16B chunk 0..7
            bf16x8 af[4], bfr[4];
#pragma unroll
            for (int i = 0; i < 4; ++i) {
                int row = wm + i * 16 + lr16;
                af[i] = *(const bf16x8*)(&sm.ab[cur][0][row * 64 + ((gck ^ (lane & 7)) * 8)]);
            }
#pragma unroll
            for (int j = 0; j < 4; ++j) {
                int row = wn + j * 16 + lr16;
                bfr[j] = *(const bf16x8*)(&sm.ab[cur][1][row * 64 + ((gck ^ (lane & 7)) * 8)]);
            }
#pragma unroll
            for (int i = 0; i < 4; ++i)
#pragma unroll
                for (int j = 0; j < 4; ++j)
                    acc[i][j] = __builtin_amdgcn_mfma_f32_16x16x32_bf16(af[i], bfr[j], acc[i][j], 0, 0, 0);
        }
        __syncthreads();                   // drains prefetch (hidden by 32-MFMA phase)
    }
#undef G1STAGE
    const int crow = (lane >> 4) * 4, ccol = lane & 15;
#pragma unroll
    for (int i = 0; i < 4; ++i)
#pragma unroll
        for (int j = 0; j < 4; ++j)
#pragma unroll
            for (int r = 0; r < 4; ++r)
                sm.cs[(wm + i * 16 + crow + r) * 136 + wn + j * 16 + ccol] =
                    __float2bfloat16(acc[i][j][r]);
    __syncthreads();
#pragma unroll
    for (int p = 0; p < 8; ++p) {
        int row = p * 16 + (tid >> 4);
        int colg = (tid & 15) * 8;
        *(uint4*)(&Bu[(size_t)(m0 + row) * N1 + n0 + colg]) =
            *(const uint4*)(&sm.cs[row * 136 + colg]);
    }
}

// ---- scan phase 1 (R9-verified): unroll-8 load batching ----
__global__ __launch_bounds__(512) void scan1(const bf16* __restrict__ Bu,
                                             const float* __restrict__ lam,
                                             float* __restrict__ Ssum) {
    int n = threadIdx.x;
    int c = blockIdx.x;
    int b = blockIdx.y;
    float lr = lam[n], li = lam[NST + n];
    const bf16* base = Bu + ((size_t)b * T_LEN + (size_t)c * CHL) * N1;
    float sr = 0.f, si = 0.f;
#pragma unroll 8
    for (int j = 0; j < CHL; ++j) {
        float br = __bfloat162float(base[(size_t)j * N1 + n]);
        float bi = __bfloat162float(base[(size_t)j * N1 + NST + n]);
        float tr = lr * sr - li * si + br;
        float ti = lr * si + li * sr + bi;
        sr = tr; si = ti;
    }
    size_t o = ((size_t)b * NCH + c) * N1 + n;
    Ssum[o] = sr; Ssum[o + NST] = si;
}

// ---- scan phase 3 (R9-verified): inline carry + unroll batching ----
__global__ __launch_bounds__(512) void scan3(bf16* __restrict__ Bu,
                                             const float* __restrict__ lam,
                                             const float* __restrict__ lamL,
                                             const float* __restrict__ Ssum) {
    int n = threadIdx.x, c = blockIdx.x, b = blockIdx.y;
    float lr = lam[n], li = lam[NST + n];
    float Lr = lamL[n], Li = lamL[NST + n];
    float pr = 0.f, pi = 0.f;
#pragma unroll 4
    for (int cp = 0; cp < c; ++cp) {
        size_t o = ((size_t)b * NCH + cp) * N1 + n;
        float sr = Ssum[o], si = Ssum[o + NST];
        float tr = Lr * pr - Li * pi + sr;
        float ti = Lr * pi + Li * pr + si;
        pr = tr; pi = ti;
    }
    float xr = pr, xi = pi;
    bf16* base = Bu + ((size_t)b * T_LEN + (size_t)c * CHL) * N1;
#pragma unroll 8
    for (int j = 0; j < CHL; ++j) {
        float br = __bfloat162float(base[(size_t)j * N1 + n]);
        float bi = __bfloat162float(base[(size_t)j * N1 + NST + n]);
        float tr = lr * xr - li * xi + br;
        float ti = lr * xi + li * xr + bi;
        xr = tr; xi = ti;
        base[(size_t)j * N1 + n]       = __float2bfloat16(xr);
        base[(size_t)j * N1 + NST + n] = __float2bfloat16(xi);
    }
}

// ---- GEMM2 v7 (R10-verified): BK=64, dbuf, T2 both-sides swizzle ----
__global__ __launch_bounds__(512) void gemm2(const bf16* __restrict__ X,
                                             const bf16* __restrict__ u,
                                             const bf16* __restrict__ W2,
                                             float* __restrict__ y) {
    __shared__ bf16 ab[2][2][128 * 64];   // 64 KB
    const int tid = threadIdx.x;
    const int m0 = blockIdx.x * 128, n0 = blockIdx.y * 128;
    const int lane = tid & 63, w = tid >> 6;
    const int wm = (w >> 2) * 64, wn = (w & 3) * 32;   // 2x4 wave grid, 64x32 each
    const int lr16 = lane & 15, kq = (lane >> 4) * 8;
    const int srow = tid >> 3;                 // 0..63: staged row within 64-row half
    const int scolx = ((tid & 7) ^ (srow & 7)) * 8;   // inverse-swizzled global col chunk

#define G2STAGE(buf, t_) do { int k0_ = (t_) * 64;                                    \
        const bf16* Asrc_; size_t lda_; int kc_;                                      \
        if (k0_ < N1) { Asrc_ = X; lda_ = N1;  kc_ = k0_; }                           \
        else          { Asrc_ = u; lda_ = DIN; kc_ = k0_ - N1; }                      \
        gl_lds16(Asrc_ + (size_t)(m0 + srow) * lda_ + kc_ + scolx,      &ab[buf][0][tid * 8]);        \
        gl_lds16(Asrc_ + (size_t)(m0 + 64 + srow) * lda_ + kc_ + scolx, &ab[buf][0][4096 + tid * 8]); \
        gl_lds16(W2 + (size_t)(n0 + srow) * K2 + k0_ + scolx,           &ab[buf][1][tid * 8]);        \
        gl_lds16(W2 + (size_t)(n0 + 64 + srow) * K2 + k0_ + scolx,      &ab[buf][1][4096 + tid * 8]); \
    } while (0)

    f32x4 acc[4][2] = {};
    G2STAGE(0, 0);                     // panel 0
    __syncthreads();
    for (int t = 0; t < 20; ++t) {
        const int cur = t & 1;
        if (t < 19) G2STAGE(cur ^ 1, t + 1);   // prefetch next panel
#pragma unroll
        for (int ks = 0; ks < 2; ++ks) {       // two 32-wide sub-panels, ascending k
            const int gck = ks * 4 + (lane >> 4);        // global 16B chunk 0..7
            bf16x8 af[4], bfr[2];
#pragma unroll
            for (int i = 0; i < 4; ++i) {
                int row = wm + i * 16 + lr16;
                af[i] = *(const bf16x8*)(&ab[cur][0][row * 64 + ((gck ^ (lane & 7)) * 8)]);
            }
#pragma unroll
            for (int j = 0; j < 2; ++j) {
                int row = wn + j * 16 + lr16;
                bfr[j] = *(const bf16x8*)(&ab[cur][1][row * 64 + ((gck ^ (lane & 7)) * 8)]);
            }
#pragma unroll
            for (int i = 0; i < 4; ++i)
#pragma unroll
                for (int j = 0; j < 2; ++j)
                    acc[i][j] = __builtin_amdgcn_mfma_f32_16x16x32_bf16(af[i], bfr[j], acc[i][j], 0, 0, 0);
        }
        __syncthreads();                   // drains prefetch (hidden by 16-MFMA phase)
    }
#undef G2STAGE
    const int crow = (lane >> 4) * 4, ccol = lane & 15;
#pragma unroll
    for (int i = 0; i < 4; ++i)
#pragma unroll
        for (int j = 0; j < 2; ++j)
#pragma unroll
            for (int r = 0; r < 4; ++r)
                y[(size_t)(m0 + wm + i * 16 + crow + r) * DOUT + n0 + wn + j * 16 + ccol] = acc[i][j][r];
}

extern "C" void kernel_launch(void* const* d_in, const int* in_sizes, int n_in,
                              void* d_out, int out_size, void* d_ws, size_t ws_size,
                              hipStream_t stream) {
    const float* u_in      = (const float*)d_in[0];
    const float* nu_log    = (const float*)d_in[1];
    const float* theta_log = (const float*)d_in[2];
    const float* gamma_log = (const float*)d_in[3];
    const float* B_real    = (const float*)d_in[4];
    const float* B_imag    = (const float*)d_in[5];
    const float* C_real    = (const float*)d_in[6];
    const float* C_imag    = (const float*)d_in[7];
    const float* Dm        = (const float*)d_in[8];
    float* y = (float*)d_out;
    char* ws = (char*)d_ws;

    bf16*  Bu   = (bf16*)ws;
    bf16*  u_bf = (bf16*)(ws + OFF_UBF);
    bf16*  Wp   = (bf16*)(ws + OFF_WP);
    bf16*  W2   = (bf16*)(ws + OFF_W2);
    float* lam  = (float*)(ws + OFF_LAM);
    float* lamL = (float*)(ws + OFF_LAML);
    float* Ssum = (float*)(ws + OFF_SSUM);

    prep<<<10496, 256, 0, stream>>>(u_in, nu_log, theta_log, gamma_log,
                                    B_real, B_imag, C_real, C_imag, Dm,
                                    u_bf, Wp, W2, lam, lamL);
    gemm1<<<dim3(M_ROWS / 128, N1 / 128), 256, 0, stream>>>(u_bf, Wp, Bu);
    scan1<<<dim3(NCH, B_SZ), 512, 0, stream>>>(Bu, lam, Ssum);
    scan3<<<dim3(NCH, B_SZ), 512, 0, stream>>>(Bu, lam, lamL, Ssum);
    gemm2<<<dim3(M_ROWS / 128, DOUT / 128), 512, 0, stream>>>(Bu, u_bf, W2, y);
}

// Round 13
// 185.732 us; speedup vs baseline: 1.0311x; 1.0311x over previous
//
#include <hip/hip_runtime.h>
#include <hip/hip_bf16.h>
#include <math.h>

#define B_SZ    8
#define T_LEN   4096
#define DIN     256
#define DOUT    256
#define NST     512
#define M_ROWS  (B_SZ * T_LEN)   // 32768
#define N1      (2 * NST)        // 1024: cols [0,512)=real plane, [512,1024)=imag plane
#define K2      (N1 + DIN)       // 1280
#define CHL     128              // scan chunk length
#define NCH     (T_LEN / CHL)    // 32

typedef __attribute__((ext_vector_type(8))) short bf16x8;
typedef __attribute__((ext_vector_type(4))) float f32x4;
typedef __hip_bfloat16 bf16;

// ws byte offsets (baseline layout)
#define OFF_UBF  67108864
#define OFF_WP   83886080
#define OFF_W2   84410368
#define OFF_LAM  85065728
#define OFF_LAML 85069824
#define OFF_SSUM 85073920

__device__ __forceinline__ void gl_lds16(const bf16* g, bf16* l) {
    __builtin_amdgcn_global_load_lds(
        (const __attribute__((address_space(1))) void*)g,
        (__attribute__((address_space(3))) void*)l, 16, 0, 0);
}

// ---- prep (baseline verbatim) ----
__global__ __launch_bounds__(256) void prep(const float* __restrict__ u,
        const float* __restrict__ nu_log, const float* __restrict__ theta_log,
        const float* __restrict__ gamma_log,
        const float* __restrict__ B_real, const float* __restrict__ B_imag,
        const float* __restrict__ C_real, const float* __restrict__ C_imag,
        const float* __restrict__ Dm,
        bf16* __restrict__ ub, bf16* __restrict__ Wp, bf16* __restrict__ W2,
        float* __restrict__ lam, float* __restrict__ lamL) {
    int bid = blockIdx.x, tid = threadIdx.x;
    if (bid < 8192) {                       // u -> bf16
        int i = bid * 256 + tid;
        float4 v = ((const float4*)u)[i];
        union { bf16 h[4]; uint2 u2; } p;
        p.h[0] = __float2bfloat16(v.x); p.h[1] = __float2bfloat16(v.y);
        p.h[2] = __float2bfloat16(v.z); p.h[3] = __float2bfloat16(v.w);
        ((uint2*)ub)[i] = p.u2;
    } else if (bid < 9216) {                // Wp (split planes) + lam/lamL
        int c = bid - 8192;                 // 0..1023
        int n = c & (NST - 1);
        float g = expf(gamma_log[n]);
        const float* src = (c < NST) ? (B_real + (size_t)n * DIN)
                                     : (B_imag + (size_t)n * DIN);
        Wp[(size_t)c * DIN + tid] = __float2bfloat16(g * src[tid]);
        int idx = c * 256 + tid;
        if (idx < NST) {
            float lm = expf(-expf(nu_log[idx]));
            float th = expf(theta_log[idx]);
            float lr = lm * cosf(th), li = lm * sinf(th);
            lam[idx] = lr; lam[NST + idx] = li;
            float ar = lr, ai = li;
#pragma unroll
            for (int q = 0; q < 7; ++q) {   // lambda^128
                float nr = ar * ar - ai * ai;
                float ni = 2.f * ar * ai;
                ar = nr; ai = ni;
            }
            lamL[idx] = ar; lamL[NST + idx] = ai;
        }
    } else {                                // W2 = [2Cr | -2Ci | D] split
        int idx = (bid - 9216) * 256 + tid;
        if (idx < DOUT * K2) {
            int o = idx / K2, c = idx - o * K2;
            float v;
            if (c < NST)            v =  2.0f * C_real[(size_t)o * NST + c];
            else if (c < 2 * NST)   v = -2.0f * C_imag[(size_t)o * NST + (c - NST)];
            else                    v =  Dm[(size_t)o * DIN + (c - 2 * NST)];
            W2[idx] = __float2bfloat16(v);
        }
    }
}

// ---- GEMM1 v8: clone of the R10-VERIFIED gemm2 v7 structure.
// 512 threads / 8 waves (2x4 grid, 64x32 per wave, acc[4][2]), BK=64
// (4 K-steps over DIN=256), both-sides XOR swizzle, dbuf __syncthreads.
// 64 KB LDS x 2 blocks/CU x 8 waves = 16 waves/CU (occupancy preserved,
// unlike R11's 256-thread BK=64 which halved TLP). Ascending-k accumulation
// unchanged -> Bu bitwise identical. Cs-union packed epilogue kept
// (store loop re-indexed for 512 threads). ----
__global__ __launch_bounds__(512) void gemm1(const bf16* __restrict__ u,
                                             const bf16* __restrict__ Wp,
                                             bf16* __restrict__ Bu) {
    __shared__ union {
        bf16 ab[2][2][128 * 64];   // [buf][A=0/B=1] 64 KB
        bf16 cs[128 * 136];        // epilogue C-tile (+8 pad), 34.8 KB
    } sm;
    const int tid = threadIdx.x;
    const int m0 = blockIdx.x * 128, n0 = blockIdx.y * 128;
    const int lane = tid & 63, w = tid >> 6;
    const int wm = (w >> 2) * 64, wn = (w & 3) * 32;   // 2x4 wave grid, 64x32 each
    const int lr16 = lane & 15;
    const int srow = tid >> 3;                        // 0..63: staged row within half
    const int scolx = ((tid & 7) ^ (srow & 7)) * 8;   // inverse-swizzled global chunk

#define G1STAGE(buf, k0) do {                                                                      \
        gl_lds16(u  + (size_t)(m0 + srow) * DIN + (k0) + scolx,      &sm.ab[buf][0][tid * 8]);        \
        gl_lds16(u  + (size_t)(m0 + 64 + srow) * DIN + (k0) + scolx, &sm.ab[buf][0][4096 + tid * 8]); \
        gl_lds16(Wp + (size_t)(n0 + srow) * DIN + (k0) + scolx,      &sm.ab[buf][1][tid * 8]);        \
        gl_lds16(Wp + (size_t)(n0 + 64 + srow) * DIN + (k0) + scolx, &sm.ab[buf][1][4096 + tid * 8]); \
    } while (0)

    f32x4 acc[4][2] = {};
    G1STAGE(0, 0);                     // panel 0
    __syncthreads();
    for (int t = 0; t < 4; ++t) {
        const int cur = t & 1;
        if (t < 3) G1STAGE(cur ^ 1, (t + 1) * 64);   // prefetch next panel
#pragma unroll
        for (int ks = 0; ks < 2; ++ks) {             // two 32-wide sub-panels, ascending k
            const int gck = ks * 4 + (lane >> 4);    // global 16B chunk 0..7
            bf16x8 af[4], bfr[2];
#pragma unroll
            for (int i = 0; i < 4; ++i) {
                int row = wm + i * 16 + lr16;
                af[i] = *(const bf16x8*)(&sm.ab[cur][0][row * 64 + ((gck ^ (lane & 7)) * 8)]);
            }
#pragma unroll
            for (int j = 0; j < 2; ++j) {
                int row = wn + j * 16 + lr16;
                bfr[j] = *(const bf16x8*)(&sm.ab[cur][1][row * 64 + ((gck ^ (lane & 7)) * 8)]);
            }
#pragma unroll
            for (int i = 0; i < 4; ++i)
#pragma unroll
                for (int j = 0; j < 2; ++j)
                    acc[i][j] = __builtin_amdgcn_mfma_f32_16x16x32_bf16(af[i], bfr[j], acc[i][j], 0, 0, 0);
        }
        __syncthreads();                   // drains prefetch (hidden by 16-MFMA phase)
    }
#undef G1STAGE
    const int crow = (lane >> 4) * 4, ccol = lane & 15;
#pragma unroll
    for (int i = 0; i < 4; ++i)
#pragma unroll
        for (int j = 0; j < 2; ++j)
#pragma unroll
            for (int r = 0; r < 4; ++r)
                sm.cs[(wm + i * 16 + crow + r) * 136 + wn + j * 16 + ccol] =
                    __float2bfloat16(acc[i][j][r]);
    __syncthreads();
#pragma unroll
    for (int p = 0; p < 4; ++p) {          // 512 threads: 4 x 32 rows
        int row = p * 32 + (tid >> 4);
        int colg = (tid & 15) * 8;
        *(uint4*)(&Bu[(size_t)(m0 + row) * N1 + n0 + colg]) =
            *(const uint4*)(&sm.cs[row * 136 + colg]);
    }
}

// ---- scan phase 1 (R9-verified): unroll-8 load batching ----
__global__ __launch_bounds__(512) void scan1(const bf16* __restrict__ Bu,
                                             const float* __restrict__ lam,
                                             float* __restrict__ Ssum) {
    int n = threadIdx.x;
    int c = blockIdx.x;
    int b = blockIdx.y;
    float lr = lam[n], li = lam[NST + n];
    const bf16* base = Bu + ((size_t)b * T_LEN + (size_t)c * CHL) * N1;
    float sr = 0.f, si = 0.f;
#pragma unroll 8
    for (int j = 0; j < CHL; ++j) {
        float br = __bfloat162float(base[(size_t)j * N1 + n]);
        float bi = __bfloat162float(base[(size_t)j * N1 + NST + n]);
        float tr = lr * sr - li * si + br;
        float ti = lr * si + li * sr + bi;
        sr = tr; si = ti;
    }
    size_t o = ((size_t)b * NCH + c) * N1 + n;
    Ssum[o] = sr; Ssum[o + NST] = si;
}

// ---- scan phase 3 (R9-verified): inline carry + unroll batching ----
__global__ __launch_bounds__(512) void scan3(bf16* __restrict__ Bu,
                                             const float* __restrict__ lam,
                                             const float* __restrict__ lamL,
                                             const float* __restrict__ Ssum) {
    int n = threadIdx.x, c = blockIdx.x, b = blockIdx.y;
    float lr = lam[n], li = lam[NST + n];
    float Lr = lamL[n], Li = lamL[NST + n];
    float pr = 0.f, pi = 0.f;
#pragma unroll 4
    for (int cp = 0; cp < c; ++cp) {
        size_t o = ((size_t)b * NCH + cp) * N1 + n;
        float sr = Ssum[o], si = Ssum[o + NST];
        float tr = Lr * pr - Li * pi + sr;
        float ti = Lr * pi + Li * pr + si;
        pr = tr; pi = ti;
    }
    float xr = pr, xi = pi;
    bf16* base = Bu + ((size_t)b * T_LEN + (size_t)c * CHL) * N1;
#pragma unroll 8
    for (int j = 0; j < CHL; ++j) {
        float br = __bfloat162float(base[(size_t)j * N1 + n]);
        float bi = __bfloat162float(base[(size_t)j * N1 + NST + n]);
        float tr = lr * xr - li * xi + br;
        float ti = lr * xi + li * xr + bi;
        xr = tr; xi = ti;
        base[(size_t)j * N1 + n]       = __float2bfloat16(xr);
        base[(size_t)j * N1 + NST + n] = __float2bfloat16(xi);
    }
}

// ---- GEMM2 v7 (R10-verified): BK=64, dbuf, T2 both-sides swizzle ----
__global__ __launch_bounds__(512) void gemm2(const bf16* __restrict__ X,
                                             const bf16* __restrict__ u,
                                             const bf16* __restrict__ W2,
                                             float* __restrict__ y) {
    __shared__ bf16 ab[2][2][128 * 64];   // 64 KB
    const int tid = threadIdx.x;
    const int m0 = blockIdx.x * 128, n0 = blockIdx.y * 128;
    const int lane = tid & 63, w = tid >> 6;
    const int wm = (w >> 2) * 64, wn = (w & 3) * 32;   // 2x4 wave grid, 64x32 each
    const int lr16 = lane & 15;
    const int srow = tid >> 3;                 // 0..63: staged row within 64-row half
    const int scolx = ((tid & 7) ^ (srow & 7)) * 8;   // inverse-swizzled global col chunk

#define G2STAGE(buf, t_) do { int k0_ = (t_) * 64;                                    \
        const bf16* Asrc_; size_t lda_; int kc_;                                      \
        if (k0_ < N1) { Asrc_ = X; lda_ = N1;  kc_ = k0_; }                           \
        else          { Asrc_ = u; lda_ = DIN; kc_ = k0_ - N1; }                      \
        gl_lds16(Asrc_ + (size_t)(m0 + srow) * lda_ + kc_ + scolx,      &ab[buf][0][tid * 8]);        \
        gl_lds16(Asrc_ + (size_t)(m0 + 64 + srow) * lda_ + kc_ + scolx, &ab[buf][0][4096 + tid * 8]); \
        gl_lds16(W2 + (size_t)(n0 + srow) * K2 + k0_ + scolx,           &ab[buf][1][tid * 8]);        \
        gl_lds16(W2 + (size_t)(n0 + 64 + srow) * K2 + k0_ + scolx,      &ab[buf][1][4096 + tid * 8]); \
    } while (0)

    f32x4 acc[4][2] = {};
    G2STAGE(0, 0);                     // panel 0
    __syncthreads();
    for (int t = 0; t < 20; ++t) {
        const int cur = t & 1;
        if (t < 19) G2STAGE(cur ^ 1, t + 1);   // prefetch next panel
#pragma unroll
        for (int ks = 0; ks < 2; ++ks) {       // two 32-wide sub-panels, ascending k
            const int gck = ks * 4 + (lane >> 4);        // global 16B chunk 0..7
            bf16x8 af[4], bfr[2];
#pragma unroll
            for (int i = 0; i < 4; ++i) {
                int row = wm + i * 16 + lr16;
                af[i] = *(const bf16x8*)(&ab[cur][0][row * 64 + ((gck ^ (lane & 7)) * 8)]);
            }
#pragma unroll
            for (int j = 0; j < 2; ++j) {
                int row = wn + j * 16 + lr16;
                bfr[j] = *(const bf16x8*)(&ab[cur][1][row * 64 + ((gck ^ (lane & 7)) * 8)]);
            }
#pragma unroll
            for (int i = 0; i < 4; ++i)
#pragma unroll
                for (int j = 0; j < 2; ++j)
                    acc[i][j] = __builtin_amdgcn_mfma_f32_16x16x32_bf16(af[i], bfr[j], acc[i][j], 0, 0, 0);
        }
        __syncthreads();                   // drains prefetch (hidden by 16-MFMA phase)
    }
#undef G2STAGE
    const int crow = (lane >> 4) * 4, ccol = lane & 15;
#pragma unroll
    for (int i = 0; i < 4; ++i)
#pragma unroll
        for (int j = 0; j < 2; ++j)
#pragma unroll
            for (int r = 0; r < 4; ++r)
                y[(size_t)(m0 + wm + i * 16 + crow + r) * DOUT + n0 + wn + j * 16 + ccol] = acc[i][j][r];
}

extern "C" void kernel_launch(void* const* d_in, const int* in_sizes, int n_in,
                              void* d_out, int out_size, void* d_ws, size_t ws_size,
                              hipStream_t stream) {
    const float* u_in      = (const float*)d_in[0];
    const float* nu_log    = (const float*)d_in[1];
    const float* theta_log = (const float*)d_in[2];
    const float* gamma_log = (const float*)d_in[3];
    const float* B_real    = (const float*)d_in[4];
    const float* B_imag    = (const float*)d_in[5];
    const float* C_real    = (const float*)d_in[6];
    const float* C_imag    = (const float*)d_in[7];
    const float* Dm        = (const float*)d_in[8];
    float* y = (float*)d_out;
    char* ws = (char*)d_ws;

    bf16*  Bu   = (bf16*)ws;
    bf16*  u_bf = (bf16*)(ws + OFF_UBF);
    bf16*  Wp   = (bf16*)(ws + OFF_WP);
    bf16*  W2   = (bf16*)(ws + OFF_W2);
    float* lam  = (float*)(ws + OFF_LAM);
    float* lamL = (float*)(ws + OFF_LAML);
    float* Ssum = (float*)(ws + OFF_SSUM);

    prep<<<10496, 256, 0, stream>>>(u_in, nu_log, theta_log, gamma_log,
                                    B_real, B_imag, C_real, C_imag, Dm,
                                    u_bf, Wp, W2, lam, lamL);
    gemm1<<<dim3(M_ROWS / 128, N1 / 128), 512, 0, stream>>>(u_bf, Wp, Bu);
    scan1<<<dim3(NCH, B_SZ), 512, 0, stream>>>(Bu, lam, Ssum);
    scan3<<<dim3(NCH, B_SZ), 512, 0, stream>>>(Bu, lam, lamL, Ssum);
    gemm2<<<dim3(M_ROWS / 128, DOUT / 128), 512, 0, stream>>>(Bu, u_bf, W2, y);
}

// Round 14
// 178.395 us; speedup vs baseline: 1.0736x; 1.0411x over previous
//
#include <hip/hip_runtime.h>
#include <hip/hip_bf16.h>
#include <math.h>

#define B_SZ    8
#define T_LEN   4096
#define DIN     256
#define DOUT    256
#define NST     512
#define M_ROWS  (B_SZ * T_LEN)   // 32768
#define N1      (2 * NST)        // 1024: cols [0,512)=real plane, [512,1024)=imag plane
#define K2      (N1 + DIN)       // 1280
#define CHL     128              // scan chunk length
#define NCH     (T_LEN / CHL)    // 32

typedef __attribute__((ext_vector_type(8))) short bf16x8;
typedef __attribute__((ext_vector_type(4))) float f32x4;
typedef __hip_bfloat16 bf16;

// ws byte offsets (baseline layout)
#define OFF_UBF  67108864
#define OFF_WP   83886080
#define OFF_W2   84410368
#define OFF_LAM  85065728
#define OFF_LAML 85069824
#define OFF_SSUM 85073920

__device__ __forceinline__ void gl_lds16(const bf16* g, bf16* l) {
    __builtin_amdgcn_global_load_lds(
        (const __attribute__((address_space(1))) void*)g,
        (__attribute__((address_space(3))) void*)l, 16, 0, 0);
}

// ---- prep (baseline verbatim) ----
__global__ __launch_bounds__(256) void prep(const float* __restrict__ u,
        const float* __restrict__ nu_log, const float* __restrict__ theta_log,
        const float* __restrict__ gamma_log,
        const float* __restrict__ B_real, const float* __restrict__ B_imag,
        const float* __restrict__ C_real, const float* __restrict__ C_imag,
        const float* __restrict__ Dm,
        bf16* __restrict__ ub, bf16* __restrict__ Wp, bf16* __restrict__ W2,
        float* __restrict__ lam, float* __restrict__ lamL) {
    int bid = blockIdx.x, tid = threadIdx.x;
    if (bid < 8192) {                       // u -> bf16
        int i = bid * 256 + tid;
        float4 v = ((const float4*)u)[i];
        union { bf16 h[4]; uint2 u2; } p;
        p.h[0] = __float2bfloat16(v.x); p.h[1] = __float2bfloat16(v.y);
        p.h[2] = __float2bfloat16(v.z); p.h[3] = __float2bfloat16(v.w);
        ((uint2*)ub)[i] = p.u2;
    } else if (bid < 9216) {                // Wp (split planes) + lam/lamL
        int c = bid - 8192;                 // 0..1023
        int n = c & (NST - 1);
        float g = expf(gamma_log[n]);
        const float* src = (c < NST) ? (B_real + (size_t)n * DIN)
                                     : (B_imag + (size_t)n * DIN);
        Wp[(size_t)c * DIN + tid] = __float2bfloat16(g * src[tid]);
        int idx = c * 256 + tid;
        if (idx < NST) {
            float lm = expf(-expf(nu_log[idx]));
            float th = expf(theta_log[idx]);
            float lr = lm * cosf(th), li = lm * sinf(th);
            lam[idx] = lr; lam[NST + idx] = li;
            float ar = lr, ai = li;
#pragma unroll
            for (int q = 0; q < 7; ++q) {   // lambda^128
                float nr = ar * ar - ai * ai;
                float ni = 2.f * ar * ai;
                ar = nr; ai = ni;
            }
            lamL[idx] = ar; lamL[NST + idx] = ai;
        }
    } else {                                // W2 = [2Cr | -2Ci | D] split
        int idx = (bid - 9216) * 256 + tid;
        if (idx < DOUT * K2) {
            int o = idx / K2, c = idx - o * K2;
            float v;
            if (c < NST)            v =  2.0f * C_real[(size_t)o * NST + c];
            else if (c < 2 * NST)   v = -2.0f * C_imag[(size_t)o * NST + (c - NST)];
            else                    v =  Dm[(size_t)o * DIN + (c - 2 * NST)];
            W2[idx] = __float2bfloat16(v);
        }
    }
}

// ---- GEMM1 (R10-verified form, 184.8us config) + T1 XCD swizzle.
// Block remap: all 8 n0-tiles of one A-tile (bx) share h%8 -> one XCD;
// per XCD 32 A-tiles x 64 KB = 2 MB fits L2 -> A re-reads become L2 hits,
// shortening each __syncthreads prefetch-drain. Work content unchanged. ----
__global__ __launch_bounds__(256) void gemm1(const bf16* __restrict__ u,
                                             const bf16* __restrict__ Wp,
                                             bf16* __restrict__ Bu) {
    __shared__ union {
        bf16 ab[2][2][128 * 32];   // [buf][A=0/B=1][row*32+col]
        bf16 cs[128 * 136];        // epilogue C-tile (+8 pad)
    } sm;
    const int tid = threadIdx.x;
    // XCD swizzle: h = bx%8 + 8*by + 64*(bx/8)  (bijective, 2048 blocks)
    const int h = blockIdx.x + blockIdx.y * gridDim.x;
    const int bx = (h & 7) + 8 * (h >> 6);
    const int by = (h >> 3) & 7;
    const int m0 = bx * 128, n0 = by * 128;
    const int lane = tid & 63, w = tid >> 6;
    const int wm = (w >> 1) * 64, wn = (w & 1) * 64;
    const int lr16 = lane & 15, kq = (lane >> 4) * 8;
    const int srow = tid >> 2, scol = (tid & 3) * 8;

    f32x4 acc[4][4] = {};
    // prologue: stage panel 0 into buf 0
    {
        gl_lds16(u  + (size_t)(m0 + srow) * DIN + scol,       &sm.ab[0][0][tid * 8]);
        gl_lds16(u  + (size_t)(m0 + 64 + srow) * DIN + scol,  &sm.ab[0][0][2048 + tid * 8]);
        gl_lds16(Wp + (size_t)(n0 + srow) * DIN + scol,       &sm.ab[0][1][tid * 8]);
        gl_lds16(Wp + (size_t)(n0 + 64 + srow) * DIN + scol,  &sm.ab[0][1][2048 + tid * 8]);
    }
    __syncthreads();
    for (int t = 0; t < 8; ++t) {
        const int cur = t & 1;
        if (t < 7) {                       // prefetch next panel into other buf
            int k0 = (t + 1) * 32;
            gl_lds16(u  + (size_t)(m0 + srow) * DIN + k0 + scol,       &sm.ab[cur ^ 1][0][tid * 8]);
            gl_lds16(u  + (size_t)(m0 + 64 + srow) * DIN + k0 + scol,  &sm.ab[cur ^ 1][0][2048 + tid * 8]);
            gl_lds16(Wp + (size_t)(n0 + srow) * DIN + k0 + scol,       &sm.ab[cur ^ 1][1][tid * 8]);
            gl_lds16(Wp + (size_t)(n0 + 64 + srow) * DIN + k0 + scol,  &sm.ab[cur ^ 1][1][2048 + tid * 8]);
        }
        bf16x8 af[4], bfr[4];
#pragma unroll
        for (int i = 0; i < 4; ++i)
            af[i] = *(const bf16x8*)(&sm.ab[cur][0][(wm + i * 16 + lr16) * 32 + kq]);
#pragma unroll
        for (int j = 0; j < 4; ++j)
            bfr[j] = *(const bf16x8*)(&sm.ab[cur][1][(wn + j * 16 + lr16) * 32 + kq]);
#pragma unroll
        for (int i = 0; i < 4; ++i)
#pragma unroll
            for (int j = 0; j < 4; ++j)
                acc[i][j] = __builtin_amdgcn_mfma_f32_16x16x32_bf16(af[i], bfr[j], acc[i][j], 0, 0, 0);
        __syncthreads();                   // drains prefetch (latency hidden by compute)
    }
    const int crow = (lane >> 4) * 4, ccol = lane & 15;
#pragma unroll
    for (int i = 0; i < 4; ++i)
#pragma unroll
        for (int j = 0; j < 4; ++j)
#pragma unroll
            for (int r = 0; r < 4; ++r)
                sm.cs[(wm + i * 16 + crow + r) * 136 + wn + j * 16 + ccol] =
                    __float2bfloat16(acc[i][j][r]);
    __syncthreads();
#pragma unroll
    for (int p = 0; p < 8; ++p) {
        int row = p * 16 + (tid >> 4);
        int colg = (tid & 15) * 8;
        *(uint4*)(&Bu[(size_t)(m0 + row) * N1 + n0 + colg]) =
            *(const uint4*)(&sm.cs[row * 136 + colg]);
    }
}

// ---- scan phase 1 (R9-verified): unroll-8 load batching ----
__global__ __launch_bounds__(512) void scan1(const bf16* __restrict__ Bu,
                                             const float* __restrict__ lam,
                                             float* __restrict__ Ssum) {
    int n = threadIdx.x;
    int c = blockIdx.x;
    int b = blockIdx.y;
    float lr = lam[n], li = lam[NST + n];
    const bf16* base = Bu + ((size_t)b * T_LEN + (size_t)c * CHL) * N1;
    float sr = 0.f, si = 0.f;
#pragma unroll 8
    for (int j = 0; j < CHL; ++j) {
        float br = __bfloat162float(base[(size_t)j * N1 + n]);
        float bi = __bfloat162float(base[(size_t)j * N1 + NST + n]);
        float tr = lr * sr - li * si + br;
        float ti = lr * si + li * sr + bi;
        sr = tr; si = ti;
    }
    size_t o = ((size_t)b * NCH + c) * N1 + n;
    Ssum[o] = sr; Ssum[o + NST] = si;
}

// ---- scan phase 3 (R9-verified): inline carry + unroll batching ----
__global__ __launch_bounds__(512) void scan3(bf16* __restrict__ Bu,
                                             const float* __restrict__ lam,
                                             const float* __restrict__ lamL,
                                             const float* __restrict__ Ssum) {
    int n = threadIdx.x, c = blockIdx.x, b = blockIdx.y;
    float lr = lam[n], li = lam[NST + n];
    float Lr = lamL[n], Li = lamL[NST + n];
    float pr = 0.f, pi = 0.f;
#pragma unroll 4
    for (int cp = 0; cp < c; ++cp) {
        size_t o = ((size_t)b * NCH + cp) * N1 + n;
        float sr = Ssum[o], si = Ssum[o + NST];
        float tr = Lr * pr - Li * pi + sr;
        float ti = Lr * pi + Li * pr + si;
        pr = tr; pi = ti;
    }
    float xr = pr, xi = pi;
    bf16* base = Bu + ((size_t)b * T_LEN + (size_t)c * CHL) * N1;
#pragma unroll 8
    for (int j = 0; j < CHL; ++j) {
        float br = __bfloat162float(base[(size_t)j * N1 + n]);
        float bi = __bfloat162float(base[(size_t)j * N1 + NST + n]);
        float tr = lr * xr - li * xi + br;
        float ti = lr * xi + li * xr + bi;
        xr = tr; xi = ti;
        base[(size_t)j * N1 + n]       = __float2bfloat16(xr);
        base[(size_t)j * N1 + NST + n] = __float2bfloat16(xi);
    }
}

// ---- GEMM2 v7 (R10-verified): BK=64, dbuf, T2 both-sides swizzle
// + T1 XCD swizzle (by in {0,1}: both X-sharing blocks colocate). ----
__global__ __launch_bounds__(512) void gemm2(const bf16* __restrict__ X,
                                             const bf16* __restrict__ u,
                                             const bf16* __restrict__ W2,
                                             float* __restrict__ y) {
    __shared__ bf16 ab[2][2][128 * 64];   // 64 KB
    const int tid = threadIdx.x;
    // XCD swizzle: h = bx%8 + 8*by + 16*(bx/8)  (bijective, 512 blocks)
    const int h = blockIdx.x + blockIdx.y * gridDim.x;
    const int bx = (h & 7) + 8 * (h >> 4);
    const int by = (h >> 3) & 1;
    const int m0 = bx * 128, n0 = by * 128;
    const int lane = tid & 63, w = tid >> 6;
    const int wm = (w >> 2) * 64, wn = (w & 3) * 32;   // 2x4 wave grid, 64x32 each
    const int lr16 = lane & 15;
    const int srow = tid >> 3;                 // 0..63: staged row within 64-row half
    const int scolx = ((tid & 7) ^ (srow & 7)) * 8;   // inverse-swizzled global col chunk

#define G2STAGE(buf, t_) do { int k0_ = (t_) * 64;                                    \
        const bf16* Asrc_; size_t lda_; int kc_;                                      \
        if (k0_ < N1) { Asrc_ = X; lda_ = N1;  kc_ = k0_; }                           \
        else          { Asrc_ = u; lda_ = DIN; kc_ = k0_ - N1; }                      \
        gl_lds16(Asrc_ + (size_t)(m0 + srow) * lda_ + kc_ + scolx,      &ab[buf][0][tid * 8]);        \
        gl_lds16(Asrc_ + (size_t)(m0 + 64 + srow) * lda_ + kc_ + scolx, &ab[buf][0][4096 + tid * 8]); \
        gl_lds16(W2 + (size_t)(n0 + srow) * K2 + k0_ + scolx,           &ab[buf][1][tid * 8]);        \
        gl_lds16(W2 + (size_t)(n0 + 64 + srow) * K2 + k0_ + scolx,      &ab[buf][1][4096 + tid * 8]); \
    } while (0)

    f32x4 acc[4][2] = {};
    G2STAGE(0, 0);                     // panel 0
    __syncthreads();
    for (int t = 0; t < 20; ++t) {
        const int cur = t & 1;
        if (t < 19) G2STAGE(cur ^ 1, t + 1);   // prefetch next panel
#pragma unroll
        for (int ks = 0; ks < 2; ++ks) {       // two 32-wide sub-panels, ascending k
            const int gck = ks * 4 + (lane >> 4);        // global 16B chunk 0..7
            bf16x8 af[4], bfr[2];
#pragma unroll
            for (int i = 0; i < 4; ++i) {
                int row = wm + i * 16 + lr16;
                af[i] = *(const bf16x8*)(&ab[cur][0][row * 64 + ((gck ^ (lane & 7)) * 8)]);
            }
#pragma unroll
            for (int j = 0; j < 2; ++j) {
                int row = wn + j * 16 + lr16;
                bfr[j] = *(const bf16x8*)(&ab[cur][1][row * 64 + ((gck ^ (lane & 7)) * 8)]);
            }
#pragma unroll
            for (int i = 0; i < 4; ++i)
#pragma unroll
                for (int j = 0; j < 2; ++j)
                    acc[i][j] = __builtin_amdgcn_mfma_f32_16x16x32_bf16(af[i], bfr[j], acc[i][j], 0, 0, 0);
        }
        __syncthreads();                   // drains prefetch (hidden by 16-MFMA phase)
    }
#undef G2STAGE
    const int crow = (lane >> 4) * 4, ccol = lane & 15;
#pragma unroll
    for (int i = 0; i < 4; ++i)
#pragma unroll
        for (int j = 0; j < 2; ++j)
#pragma unroll
            for (int r = 0; r < 4; ++r)
                y[(size_t)(m0 + wm + i * 16 + crow + r) * DOUT + n0 + wn + j * 16 + ccol] = acc[i][j][r];
}

extern "C" void kernel_launch(void* const* d_in, const int* in_sizes, int n_in,
                              void* d_out, int out_size, void* d_ws, size_t ws_size,
                              hipStream_t stream) {
    const float* u_in      = (const float*)d_in[0];
    const float* nu_log    = (const float*)d_in[1];
    const float* theta_log = (const float*)d_in[2];
    const float* gamma_log = (const float*)d_in[3];
    const float* B_real    = (const float*)d_in[4];
    const float* B_imag    = (const float*)d_in[5];
    const float* C_real    = (const float*)d_in[6];
    const float* C_imag    = (const float*)d_in[7];
    const float* Dm        = (const float*)d_in[8];
    float* y = (float*)d_out;
    char* ws = (char*)d_ws;

    bf16*  Bu   = (bf16*)ws;
    bf16*  u_bf = (bf16*)(ws + OFF_UBF);
    bf16*  Wp   = (bf16*)(ws + OFF_WP);
    bf16*  W2   = (bf16*)(ws + OFF_W2);
    float* lam  = (float*)(ws + OFF_LAM);
    float* lamL = (float*)(ws + OFF_LAML);
    float* Ssum = (float*)(ws + OFF_SSUM);

    prep<<<10496, 256, 0, stream>>>(u_in, nu_log, theta_log, gamma_log,
                                    B_real, B_imag, C_real, C_imag, Dm,
                                    u_bf, Wp, W2, lam, lamL);
    gemm1<<<dim3(M_ROWS / 128, N1 / 128), 256, 0, stream>>>(u_bf, Wp, Bu);
    scan1<<<dim3(NCH, B_SZ), 512, 0, stream>>>(Bu, lam, Ssum);
    scan3<<<dim3(NCH, B_SZ), 512, 0, stream>>>(Bu, lam, lamL, Ssum);
    gemm2<<<dim3(M_ROWS / 128, DOUT / 128), 512, 0, stream>>>(Bu, u_bf, W2, y);
}